// Round 13
// baseline (266.718 us; speedup 1.0000x reference)
//
#include <hip/hip_runtime.h>

#define F 64
#define H 64
#define NT 256
#define TILE_ROWS 128     // 4 waves x 32 wave-private rows
#define ITERS 8
#define ROWS_PER_BLOCK (TILE_ROWS * ITERS)   // 1024
#define WPAD 72   // LDS row stride in bf16 elems (144 B)

typedef __bf16 bf16;
typedef __attribute__((ext_vector_type(8))) __bf16 bf16x8;
typedef __attribute__((ext_vector_type(4))) __bf16 bf16x4;
typedef __attribute__((ext_vector_type(4))) float f32x4;

__device__ __forceinline__ float celu1(float v) {
    // CELU(alpha=1): x>0 ? x : exp(x)-1
    float e = __expf(v) - 1.0f;
    return v > 0.0f ? v : e;
}

// Single kernel, sized for the 128-reg unified cap (gfx950 insight from R12: VGPR_Count
// reports only the arch half of the unified VGPR+AGPR budget; (NT,3) capped us at 3
// waves/SIMD all along -- occupancy was reg-bound, not LDS-bound).
// Block = one feature f x 1024 rows; 4 waves x 32 wave-private hbuf rows per 128-row tile.
// Layer-in is RANK-1 -> computed with per-lane scalar FMA directly into hidden-0's
// B-fragment registers (no MFMA, no A1/B1 regs, no LDS round-trip, exact fp32).
// BOTH hidden weight sets live in LDS (wlds, bf16); fragments are read per-m inside the
// loop so only 8 regs are transient. Live set ~120 -> fits (NT,4) cap 128 without the
// spill signature (FETCH>300MB + huge WRITE; measured R4/R5/R9/R12).
// Hidden layers MFMA on C^T[out][batch]: A[m=out][k=in] (from wlds), B[k=in][n=batch]
// (regs / hbuf), D: col=batch=l15, row=out=16m+4q+rr.
__global__ __launch_bounds__(NT, 4) void mlp64(
    const float* __restrict__ x,      // [B,F]
    const float* __restrict__ w_in,
    const float* __restrict__ b_in,
    const float* __restrict__ w_hid,
    const float* __restrict__ b_hid,
    const float* __restrict__ w_out,
    const float* __restrict__ b_out,
    float* __restrict__ out,          // [B,F]
    int Btot)
{
    const int f    = blockIdx.x & (F - 1);
    const int blk  = blockIdx.x >> 6;
    const int row0 = blk * ROWS_PER_BLOCK;
    const int t    = threadIdx.x;
    const int lane = t & 63;
    const int wave = t >> 6;
    const int l15  = lane & 15;
    const int q    = lane >> 4;
    const int wrow = wave * 32;

    __shared__ __align__(16) bf16 hbuf[TILE_ROWS][WPAD];   // 18.4 KB (hidden-0 out only)
    __shared__ __align__(16) bf16 wlds[2][H][WPAD];        // 18.4 KB both hidden layers
    __shared__ __align__(16) float s_bias[2][H];           // hidden biases

    // ---- stage both hidden layers' weights into LDS (fp32 -> bf16) ----
    for (int idx = t; idx < 1024; idx += NT) {
        const int l = idx >> 9, rc = idx & 511, row = rc >> 3, ch = rc & 7;
        const float* p = w_hid + (((size_t)l * F + f) << 12) + (row << 6) + (ch << 3);
        float4 a = *(const float4*)p, b = *(const float4*)(p + 4);
        bf16x8 v;
        v[0] = (bf16)a.x; v[1] = (bf16)a.y; v[2] = (bf16)a.z; v[3] = (bf16)a.w;
        v[4] = (bf16)b.x; v[5] = (bf16)b.y; v[6] = (bf16)b.z; v[7] = (bf16)b.w;
        *(bf16x8*)&wlds[l][row][ch * 8] = v;
    }
    if (t < H)          s_bias[0][t]     = b_hid[f * H + t];
    else if (t < 2 * H) s_bias[1][t - H] = b_hid[F * H + f * H + (t - H)];
    __syncthreads();

    // ---- per-lane layer-in weights: in-index = 32kk + 8q + j  (16 regs each) ----
    float w16[16], b16[16];
    {
        const float* wp = w_in + f * H + q * 8;
        const float* bp = b_in + f * H + q * 8;
        #pragma unroll
        for (int kk = 0; kk < 2; ++kk) {
            float4 a = *(const float4*)(wp + kk * 32), b = *(const float4*)(wp + kk * 32 + 4);
            float4 c = *(const float4*)(bp + kk * 32), d = *(const float4*)(bp + kk * 32 + 4);
            w16[kk*8+0]=a.x; w16[kk*8+1]=a.y; w16[kk*8+2]=a.z; w16[kk*8+3]=a.w;
            w16[kk*8+4]=b.x; w16[kk*8+5]=b.y; w16[kk*8+6]=b.z; w16[kk*8+7]=b.w;
            b16[kk*8+0]=c.x; b16[kk*8+1]=c.y; b16[kk*8+2]=c.z; b16[kk*8+3]=c.w;
            b16[kk*8+4]=d.x; b16[kk*8+5]=d.y; b16[kk*8+6]=d.z; b16[kk*8+7]=d.w;
        }
    }

    f32x4 wo4[4];
    #pragma unroll
    for (int m = 0; m < 4; ++m)
        wo4[m] = *(const f32x4*)(w_out + f * H + m * 16 + q * 4);
    const float bo = b_out[f];

    // x: batch index = l15 within each 16-row group (4-way broadcast across quads -> L1)
    float xc0 = x[(size_t)(row0 + wrow + l15) * F + f];
    float xc1 = x[(size_t)(row0 + wrow + 16 + l15) * F + f];

    #pragma unroll 1
    for (int it = 0; it < ITERS; ++it) {
        const int rbase = row0 + it * TILE_ROWS + wrow;

        float xn0 = 0.0f, xn1 = 0.0f;
        if (it + 1 < ITERS) {
            xn0 = x[(size_t)(rbase + TILE_ROWS + l15) * F + f];
            xn1 = x[(size_t)(rbase + TILE_ROWS + 16 + l15) * F + f];
        }

        // ---- layer in->H: rank-1 directly into B-fragments (exact fp32 fma + celu) ----
        bf16x8 Bh[2][2];   // [n][kk]: B[k=32kk+8q+j][batch=n*16+l15]
        #pragma unroll
        for (int n = 0; n < 2; ++n) {
            const float xv = n ? xc1 : xc0;
            #pragma unroll
            for (int kk = 0; kk < 2; ++kk) {
                bf16x8 v;
                #pragma unroll
                for (int j = 0; j < 8; ++j)
                    v[j] = (bf16)celu1(fmaf(xv, w16[kk * 8 + j], b16[kk * 8 + j]));
                Bh[n][kk] = v;
            }
        }

        // ---- hidden layer 0 (weights from LDS, fragments transient) ----
        #pragma unroll
        for (int m = 0; m < 4; ++m) {
            bf16x8 A0 = *(const bf16x8*)&wlds[0][m * 16 + l15][q * 8];
            bf16x8 A1 = *(const bf16x8*)&wlds[0][m * 16 + l15][32 + q * 8];
            f32x4 c0  = *(const f32x4*)&s_bias[0][m * 16 + q * 4];
            #pragma unroll
            for (int n = 0; n < 2; ++n) {
                f32x4 a = __builtin_amdgcn_mfma_f32_16x16x32_bf16(A0, Bh[n][0], c0, 0, 0, 0);
                a       = __builtin_amdgcn_mfma_f32_16x16x32_bf16(A1, Bh[n][1], a, 0, 0, 0);
                bf16x4 o;
                #pragma unroll
                for (int rr = 0; rr < 4; ++rr) o[rr] = (bf16)celu1(a[rr]);
                *(bf16x4*)&hbuf[wrow + n * 16 + l15][m * 16 + q * 4] = o;
            }
        }

        // ---- hidden layer 1 (weights from LDS) + output dot in registers ----
        {
            bf16x8 Bg[2][2];
            #pragma unroll
            for (int n = 0; n < 2; ++n)
                #pragma unroll
                for (int kk = 0; kk < 2; ++kk)
                    Bg[n][kk] = *(const bf16x8*)&hbuf[wrow + n * 16 + l15][kk * 32 + q * 8];
            float s0 = 0.0f, s1 = 0.0f;
            #pragma unroll
            for (int m = 0; m < 4; ++m) {
                bf16x8 A0 = *(const bf16x8*)&wlds[1][m * 16 + l15][q * 8];
                bf16x8 A1 = *(const bf16x8*)&wlds[1][m * 16 + l15][32 + q * 8];
                f32x4 c0  = *(const f32x4*)&s_bias[1][m * 16 + q * 4];
                f32x4 a0 = __builtin_amdgcn_mfma_f32_16x16x32_bf16(A0, Bg[0][0], c0, 0, 0, 0);
                a0       = __builtin_amdgcn_mfma_f32_16x16x32_bf16(A1, Bg[0][1], a0, 0, 0, 0);
                f32x4 a1 = __builtin_amdgcn_mfma_f32_16x16x32_bf16(A0, Bg[1][0], c0, 0, 0, 0);
                a1       = __builtin_amdgcn_mfma_f32_16x16x32_bf16(A1, Bg[1][1], a1, 0, 0, 0);
                #pragma unroll
                for (int rr = 0; rr < 4; ++rr) {
                    s0 = fmaf(celu1(a0[rr]), wo4[m][rr], s0);
                    s1 = fmaf(celu1(a1[rr]), wo4[m][rr], s1);
                }
            }
            s0 += __shfl_xor(s0, 16, 64);
            s0 += __shfl_xor(s0, 32, 64);
            s1 += __shfl_xor(s1, 16, 64);
            s1 += __shfl_xor(s1, 32, 64);
            if (q == 0) {
                out[(size_t)(rbase + l15) * F + f]      = s0 + bo;
                out[(size_t)(rbase + 16 + l15) * F + f] = s1 + bo;
            }
        }

        xc0 = xn0; xc1 = xn1;
    }
}

extern "C" void kernel_launch(void* const* d_in, const int* in_sizes, int n_in,
                              void* d_out, int out_size, void* d_ws, size_t ws_size,
                              hipStream_t stream) {
    const float* x     = (const float*)d_in[0];
    const float* w_in  = (const float*)d_in[1];
    const float* b_in  = (const float*)d_in[2];
    const float* w_hid = (const float*)d_in[3];
    const float* b_hid = (const float*)d_in[4];
    const float* w_out = (const float*)d_in[5];
    const float* b_out = (const float*)d_in[6];
    float* out = (float*)d_out;

    const int Btot = in_sizes[0] / F;                       // 32768
    dim3 grid((unsigned)((Btot / ROWS_PER_BLOCK) * F));     // 2048 blocks
    dim3 block(NT);
    mlp64<<<grid, block, 0, stream>>>(x, w_in, b_in, w_hid, b_hid, w_out, b_out, out, Btot);
}